// Round 4
// baseline (252.383 us; speedup 1.0000x reference)
//
#include <hip/hip_runtime.h>
#include <stdint.h>

#define DDIM   1024
#define M_TOT  8192
#define N_ROWS 4096
#define NCELL  528             // 32x32 tile triangle, J<=I
#define SLOT   16384           // one half-tile: 128 rows x 64 k x 2B
#define NSLOT  10
#define LDS_TOTAL (NSLOT * SLOT)   // 163840 = 160 KiB

typedef __attribute__((ext_vector_type(8))) short bf16x8;
typedef __attribute__((ext_vector_type(4))) float f32x4;

__device__ __forceinline__ unsigned short f2bf(float x) {
  union { float f; uint32_t u; } v; v.f = x;
  uint32_t r = v.u + 0x7FFFu + ((v.u >> 16) & 1u);
  return (unsigned short)(r >> 16);
}

__device__ __forceinline__ void gload_lds16(const void* g, void* l) {
  __builtin_amdgcn_global_load_lds(
      (const __attribute__((address_space(1))) uint32_t*)g,
      (__attribute__((address_space(3))) uint32_t*)l, 16, 0, 0);
}

// ---------- kernel 1: row-normalize both inputs, emit bf16 z, pos/align sums ----------
__global__ __launch_bounds__(256) void knorm(const float* __restrict__ p1,
                                             const float* __restrict__ p2,
                                             unsigned short* __restrict__ z,
                                             float* __restrict__ scal) {
  const int r = blockIdx.x;
  const int t = threadIdx.x;
  const int lane = t & 63, w = t >> 6;
  __shared__ float red0[4], red1[4];

  const float4 a = ((const float4*)(p1 + (size_t)r * DDIM))[t];
  const float4 b = ((const float4*)(p2 + (size_t)r * DDIM))[t];
  float s1 = a.x*a.x + a.y*a.y + a.z*a.z + a.w*a.w;
  float s2 = b.x*b.x + b.y*b.y + b.z*b.z + b.w*b.w;
  for (int off = 1; off < 64; off <<= 1) { s1 += __shfl_xor(s1, off); s2 += __shfl_xor(s2, off); }
  if (lane == 0) { red0[w] = s1; red1[w] = s2; }
  __syncthreads();
  const float S1 = red0[0] + red0[1] + red0[2] + red0[3];
  const float S2 = red1[0] + red1[1] + red1[2] + red1[3];
  const float r1 = 1.0f / sqrtf(S1);
  const float r2 = 1.0f / sqrtf(S2);
  const float n1x = a.x*r1, n1y = a.y*r1, n1z = a.z*r1, n1w = a.w*r1;
  const float n2x = b.x*r2, n2y = b.y*r2, n2z = b.z*r2, n2w = b.w*r2;
  float pos = n1x*n2x + n1y*n2y + n1z*n2z + n1w*n2w;
  float al  = (n1x-n2x)*(n1x-n2x) + (n1y-n2y)*(n1y-n2y)
            + (n1z-n2z)*(n1z-n2z) + (n1w-n2w)*(n1w-n2w);
  __syncthreads();
  for (int off = 1; off < 64; off <<= 1) { pos += __shfl_xor(pos, off); al += __shfl_xor(al, off); }
  if (lane == 0) { red0[w] = pos; red1[w] = al; }
  __syncthreads();
  if (t == 0) {
    atomicAdd(&scal[0], red0[0] + red0[1] + red0[2] + red0[3]);
    atomicAdd(&scal[1], red1[0] + red1[1] + red1[2] + red1[3]);
  }
  ushort4 o1, o2;
  o1.x = f2bf(n1x); o1.y = f2bf(n1y); o1.z = f2bf(n1z); o1.w = f2bf(n1w);
  o2.x = f2bf(n2x); o2.y = f2bf(n2y); o2.z = f2bf(n2z); o2.w = f2bf(n2w);
  ((ushort4*)(z + (size_t)r * DDIM))[t] = o1;
  ((ushort4*)(z + (size_t)(r + N_ROWS) * DDIM))[t] = o2;
}

// stage one half-tile (128 rows x 64 k) into ring slot h%10.
// halves of K-tile kt: h=4kt+{0,1}=A rows 0-127/128-255, {2,3}=B cols 0-127/128-255.
// Linear LDS dest; source pre-swizzled by the same (row&7) chunk-XOR as the reads.
__device__ __forceinline__ void stage_half(const char* zb, int rowA0, int colB0,
                                           int h, char* lds, int tid) {
  const int part = h & 3;
  const int kbyte = (h >> 2) * 128;
  char* base = lds + (h % NSLOT) * SLOT;
  const int r0 = tid >> 3;                    // 0..63
  const int ch = tid & 7;
  const int csrc = (ch ^ (r0 & 7)) << 4;      // r&7 == r0&7 (64 ≡ 0 mod 8)
  const int g0 = (part < 2) ? (rowA0 + part * 128) : (colB0 + (part - 2) * 128);
#pragma unroll
  for (int q = 0; q < 2; ++q) {
    const int r = q * 64 + r0;
    gload_lds16(zb + (size_t)(g0 + r) * 2048 + kbyte + csrc,
                base + r * 128 + ch * 16);
  }
}

// ---------- kernel 2: fused z@z^T, 8-phase schedule, triangle 256^2 cells ----------
__global__ __launch_bounds__(512, 2) void kgemm(const unsigned short* __restrict__ z,
                                                float* __restrict__ denom,
                                                float* __restrict__ scal) {
  extern __shared__ char lds[];
  const int tid  = threadIdx.x;
  const int lane = tid & 63, wid = tid >> 6;
  const int wsr  = wid >> 2, wsc = wid & 3;   // 2M x 4N waves; wave tile 128x64
  const int lr = lane >> 4, lc = lane & 15;

  // bijective XCD swizzle (528 = 8*66), then triangle decode (row-major, J<=I)
  const int cell = (blockIdx.x & 7) * 66 + (blockIdx.x >> 3);
  int I = (int)((sqrtf(8.0f * (float)cell + 1.0f) - 1.0f) * 0.5f);
  while ((I + 1) * (I + 2) / 2 <= cell) ++I;
  while (I * (I + 1) / 2 > cell) --I;
  const int J = cell - I * (I + 1) / 2;
  const int rowA0 = I * 256, colB0 = J * 256;
  const char* zb = (const char*)z;

  f32x4 acc[8][4] = {};

  // per-lane constant pieces of the swizzled ds_read address
  const int xoff0 = (lr * 16) ^ ((lc & 7) << 4);
  const int xoff1 = (64 + lr * 16) ^ ((lc & 7) << 4);
  const int bcol  = (wsc & 1) * 64;           // col base within B half

  // prologue: issue halves H0..H5 (12 loads); wait H0..H3 landed (vmcnt 12->4)
#pragma unroll
  for (int h = 0; h < 6; ++h) stage_half(zb, rowA0, colB0, h, lds, tid);
  asm volatile("s_waitcnt vmcnt(4)" ::: "memory");
  asm volatile("s_barrier" ::: "memory");

  for (int T = 0; T < 16; ++T) {
    const char* aBase = lds + ((4 * T + wsr) % NSLOT) * SLOT;
    const char* bBase = lds + ((4 * T + 2 + (wsc >> 1)) % NSLOT) * SLOT;
#pragma unroll
    for (int ph = 0; ph < 4; ++ph) {
      const int mq = ph >> 1, kk = ph & 1;
      const int xo = kk ? xoff1 : xoff0;
      bf16x8 af[4], bg[4];
#pragma unroll
      for (int j = 0; j < 4; ++j)
        af[j] = *(const bf16x8*)(aBase + (mq * 64 + j * 16 + lc) * 128 + xo);
#pragma unroll
      for (int n = 0; n < 4; ++n)
        bg[n] = *(const bf16x8*)(bBase + (bcol + n * 16 + lc) * 128 + xo);
      const int g = T * 4 + ph;
      if (g + 6 < 64) stage_half(zb, rowA0, colB0, g + 6, lds, tid);
      asm volatile("s_barrier" ::: "memory");
      asm volatile("s_waitcnt lgkmcnt(0)" ::: "memory");
      __builtin_amdgcn_sched_barrier(0);
      __builtin_amdgcn_s_setprio(1);
#pragma unroll
      for (int j = 0; j < 4; ++j)
#pragma unroll
        for (int n = 0; n < 4; ++n)
          acc[mq * 4 + j][n] =
              __builtin_amdgcn_mfma_f32_16x16x32_bf16(af[j], bg[n], acc[mq * 4 + j][n], 0, 0, 0);
      __builtin_amdgcn_s_setprio(0);
      __builtin_amdgcn_sched_barrier(0);
      if (ph == 3) {
        if (T <= 13) asm volatile("s_waitcnt vmcnt(4)" ::: "memory");
        else         asm volatile("s_waitcnt vmcnt(0)" ::: "memory");
      }
      asm volatile("s_barrier" ::: "memory");
    }
  }

  // ---- fused epilogue: strict-lower mask, row-sums + col-sums + unif ----
  const float RK10 = 14.426950408889634f;  // 10 * log2(e)
  const float K4   = 5.770780163555856f;   // 4 * log2(e)
  const bool unif = (I <= 7) || (I >= 8 && I <= 15 && J >= 8);
  const int  uidx = (I <= 7) ? 2 : 3;
  float u = 0.0f;
  float cs[4] = {0.0f, 0.0f, 0.0f, 0.0f};

#pragma unroll
  for (int m = 0; m < 8; ++m) {
    const int growb = rowA0 + wsr * 128 + m * 16 + lr * 4;
#pragma unroll
    for (int i = 0; i < 4; ++i) {
      const int grow = growb + i;
      float rs = 0.0f;
#pragma unroll
      for (int n = 0; n < 4; ++n) {
        const int gcol = colB0 + wsc * 64 + n * 16 + lc;
        const bool incl = (gcol < grow);
        float e = incl ? exp2f(acc[m][n][i] * RK10) : 0.0f;
        rs += e;
        cs[n] += e;
        if (unif) u += incl ? exp2f(acc[m][n][i] * K4 - K4) : 0.0f;
      }
      rs += __shfl_xor(rs, 1); rs += __shfl_xor(rs, 2);
      rs += __shfl_xor(rs, 4); rs += __shfl_xor(rs, 8);
      if (lc == 0) atomicAdd(&denom[grow], rs);
    }
  }
#pragma unroll
  for (int n = 0; n < 4; ++n) {
    float c = cs[n];
    c += __shfl_xor(c, 16); c += __shfl_xor(c, 32);
    if (lr == 0) atomicAdd(&denom[colB0 + wsc * 64 + n * 16 + lc], c);
  }
  if (unif) {
    for (int off = 1; off < 64; off <<= 1) u += __shfl_xor(u, off);
    float* red = (float*)lds;
    __syncthreads();
    if (lane == 0) red[wid] = u;
    __syncthreads();
    if (tid == 0) {
      float s8 = 0.0f;
#pragma unroll
      for (int i = 0; i < 8; ++i) s8 += red[i];
      atomicAdd(&scal[uidx], 2.0f * s8);   // each pair once; mirror via x2 (kfinal halves)
    }
  }
}

// ---------- kernel 3: sum(log(denom)) + final combine (single block) ----------
__global__ __launch_bounds__(1024) void klogf(const float* __restrict__ denom,
                                              const float* __restrict__ scal,
                                              float* __restrict__ out) {
  __shared__ float red[16];
  const int tid = threadIdx.x;
  float s = 0.0f;
#pragma unroll
  for (int q = 0; q < 8; ++q) s += logf(denom[q * 1024 + tid]);
  const int lane = tid & 63, w = tid >> 6;
  for (int off = 1; off < 64; off <<= 1) s += __shfl_xor(s, off);
  if (lane == 0) red[w] = s;
  __syncthreads();
  if (tid == 0) {
    float S = 0.0f;
#pragma unroll
    for (int i = 0; i < 16; ++i) S += red[i];
    const float P = 2048.0f * 2047.0f * 0.5f;
    out[0] = (S - 20.0f * scal[0]) / 8192.0f;   // (sum log d - 2*sum_pos/t) / 2n
    out[1] = scal[1] / 4096.0f;                 // lalign
    out[2] = 0.5f * (logf(scal[2] * 0.5f / P) + logf(scal[3] * 0.5f / P));
  }
}

extern "C" void kernel_launch(void* const* d_in, const int* in_sizes, int n_in,
                              void* d_out, int out_size, void* d_ws, size_t ws_size,
                              hipStream_t stream) {
  const float* p1 = (const float*)d_in[0];
  const float* p2 = (const float*)d_in[1];
  float* out = (float*)d_out;
  char* ws = (char*)d_ws;
  unsigned short* z = (unsigned short*)ws;                    // 8192 x 1024 bf16 = 16 MB
  float* denom = (float*)(ws + (size_t)M_TOT * DDIM * 2);     // 8192 f32
  float* scal  = denom + M_TOT;                               // [pos, align, U0, U1]

  (void)hipFuncSetAttribute((const void*)kgemm,
                            hipFuncAttributeMaxDynamicSharedMemorySize, LDS_TOTAL);
  hipMemsetAsync(denom, 0, (M_TOT + 8) * sizeof(float), stream);
  knorm<<<N_ROWS, 256, 0, stream>>>(p1, p2, z, scal);
  kgemm<<<NCELL, 512, LDS_TOTAL, stream>>>(z, denom, scal);
  klogf<<<1, 1024, 0, stream>>>(denom, scal, out);
}

// Round 5
// 146.309 us; speedup vs baseline: 1.7250x; 1.7250x over previous
//
#include <hip/hip_runtime.h>
#include <stdint.h>

#define DDIM   1024
#define M_TOT  8192
#define N_ROWS 4096
#define KT     16              // 1024 / BK=64
#define NCELL  1056            // cells 256 rows x 128 cols, J <= 2I+1
#define ASLOT  32768           // 256 rows x 64 k x 2B
#define BSLOT  16384           // 128 rows x 64 k x 2B
#define LDS_TOTAL (3*ASLOT + 3*BSLOT + 128)

typedef __attribute__((ext_vector_type(8))) short bf16x8;
typedef __attribute__((ext_vector_type(4))) float f32x4;

__device__ __forceinline__ unsigned short f2bf(float x) {
  union { float f; uint32_t u; } v; v.f = x;
  uint32_t r = v.u + 0x7FFFu + ((v.u >> 16) & 1u);
  return (unsigned short)(r >> 16);
}

__device__ __forceinline__ void gload_lds16(const void* g, void* l) {
  __builtin_amdgcn_global_load_lds(
      (const __attribute__((address_space(1))) uint32_t*)g,
      (__attribute__((address_space(3))) uint32_t*)l, 16, 0, 0);
}

// ---------- kernel 1: row-normalize, emit bf16 z, per-row pos/align partials ----------
// NO same-address atomics (R4 post-mortem: 8192 serialized atomics ~= the 100us tail).
__global__ __launch_bounds__(256) void knorm(const float* __restrict__ p1,
                                             const float* __restrict__ p2,
                                             unsigned short* __restrict__ z,
                                             float* __restrict__ pp,
                                             float* __restrict__ ap) {
  const int r = blockIdx.x;
  const int t = threadIdx.x;
  const int lane = t & 63, w = t >> 6;
  __shared__ float red0[4], red1[4];

  const float4 a = ((const float4*)(p1 + (size_t)r * DDIM))[t];
  const float4 b = ((const float4*)(p2 + (size_t)r * DDIM))[t];
  float s1 = a.x*a.x + a.y*a.y + a.z*a.z + a.w*a.w;
  float s2 = b.x*b.x + b.y*b.y + b.z*b.z + b.w*b.w;
  for (int off = 1; off < 64; off <<= 1) { s1 += __shfl_xor(s1, off); s2 += __shfl_xor(s2, off); }
  if (lane == 0) { red0[w] = s1; red1[w] = s2; }
  __syncthreads();
  const float S1 = red0[0] + red0[1] + red0[2] + red0[3];
  const float S2 = red1[0] + red1[1] + red1[2] + red1[3];
  const float r1 = 1.0f / sqrtf(S1);
  const float r2 = 1.0f / sqrtf(S2);
  const float n1x = a.x*r1, n1y = a.y*r1, n1z = a.z*r1, n1w = a.w*r1;
  const float n2x = b.x*r2, n2y = b.y*r2, n2z = b.z*r2, n2w = b.w*r2;
  float pos = n1x*n2x + n1y*n2y + n1z*n2z + n1w*n2w;
  float al  = (n1x-n2x)*(n1x-n2x) + (n1y-n2y)*(n1y-n2y)
            + (n1z-n2z)*(n1z-n2z) + (n1w-n2w)*(n1w-n2w);
  __syncthreads();
  for (int off = 1; off < 64; off <<= 1) { pos += __shfl_xor(pos, off); al += __shfl_xor(al, off); }
  if (lane == 0) { red0[w] = pos; red1[w] = al; }
  __syncthreads();
  if (t == 0) {
    pp[r] = red0[0] + red0[1] + red0[2] + red0[3];
    ap[r] = red1[0] + red1[1] + red1[2] + red1[3];
  }
  ushort4 o1, o2;
  o1.x = f2bf(n1x); o1.y = f2bf(n1y); o1.z = f2bf(n1z); o1.w = f2bf(n1w);
  o2.x = f2bf(n2x); o2.y = f2bf(n2y); o2.z = f2bf(n2z); o2.w = f2bf(n2w);
  ((ushort4*)(z + (size_t)r * DDIM))[t] = o1;
  ((ushort4*)(z + (size_t)(r + N_ROWS) * DDIM))[t] = o2;
}

// stage one 64-K-tile of A (256 rows) + B (128 rows) into LDS slot (R3-proven).
__device__ __forceinline__ void stage_tile(const char* zb, int rowA0, int colB0,
                                           int kt, char* As, char* Bs, int tid) {
  const int rsub = tid >> 3;                 // 0..63
  const int ch   = tid & 7;                  // 16B chunk in 128B row
  const int csrc = (ch ^ (rsub & 7)) << 4;   // pre-swizzled source (rule #21)
  const int kb   = kt * 128;
#pragma unroll
  for (int q = 0; q < 4; ++q) {
    const int row = q * 64 + rsub;
    gload_lds16(zb + (size_t)(rowA0 + row) * 2048 + kb + csrc, As + row * 128 + ch * 16);
  }
#pragma unroll
  for (int q = 0; q < 2; ++q) {
    const int row = q * 64 + rsub;
    gload_lds16(zb + (size_t)(colB0 + row) * 2048 + kb + csrc, Bs + row * 128 + ch * 16);
  }
}

// ---------- kernel 2: persistent fused z@z^T, dynamic work-stealing over triangle cells ----------
__global__ __launch_bounds__(512) void kgemm(const unsigned short* __restrict__ z,
                                             float* __restrict__ denom,
                                             float* __restrict__ scal,
                                             int* __restrict__ ctr) {
  extern __shared__ char lds[];
  char* AsBase = lds;
  char* BsBase = lds + 3 * ASLOT;
  float* red   = (float*)(lds + 3 * ASLOT + 3 * BSLOT);
  int*  cellp  = (int*)(lds + 3 * ASLOT + 3 * BSLOT + 64);

  const int tid  = threadIdx.x;
  const int lane = tid & 63, wid = tid >> 6;
  const int wsr  = wid >> 1, wsc = wid & 1;   // 4M x 2N waves, wave tile 64x64
  const int lr = lane >> 4, lc = lane & 15;
  const char* zb = (const char*)z;
  const float RK10 = 14.426950408889634f;  // 10 * log2(e)
  const float K4   = 5.770780163555856f;   // 4 * log2(e)

  while (true) {
    __syncthreads();
    if (tid == 0) *cellp = atomicAdd(ctr, 1);
    __syncthreads();
    const int cell = *cellp;
    if (cell >= NCELL) break;

    int I = (int)((sqrtf(4.0f * (float)cell + 1.0f) - 1.0f) * 0.5f);
    while ((I + 1) * (I + 2) <= cell) ++I;
    while (I * (I + 1) > cell) --I;
    const int J = cell - I * (I + 1);
    const int rowA0 = I * 256, colB0 = J * 128;
    // wave-uniform: does this wave's 64x64 quadrant contain any strict-lower element?
    const bool useful = (colB0 + wsc * 64) < (rowA0 + wsr * 64 + 64);

    f32x4 acc[4][4] = {};
    stage_tile(zb, rowA0, colB0, 0, AsBase, BsBase, tid);
    stage_tile(zb, rowA0, colB0, 1, AsBase + ASLOT, BsBase + BSLOT, tid);
    asm volatile("s_waitcnt vmcnt(6)" ::: "memory");
    __builtin_amdgcn_s_barrier();
    __builtin_amdgcn_sched_barrier(0);

    for (int t = 0; t < KT; ++t) {
      if (t + 2 < KT) {
        const int s2 = (t + 2) % 3;
        stage_tile(zb, rowA0, colB0, t + 2, AsBase + s2 * ASLOT, BsBase + s2 * BSLOT, tid);
      }
      __builtin_amdgcn_sched_barrier(0);
      const int s = t % 3;
      const char* At = AsBase + s * ASLOT;
      const char* Bt = BsBase + s * BSLOT;
      if (useful) {
        bf16x8 af[4][2], bg[4][2];
        const int sw = (lc & 7) << 4;
#pragma unroll
        for (int m = 0; m < 4; ++m) {
          const int r = wsr * 64 + m * 16 + lc;
#pragma unroll
          for (int kk = 0; kk < 2; ++kk)
            af[m][kk] = *(const bf16x8*)(At + r * 128 + ((kk * 64 + lr * 16) ^ sw));
        }
#pragma unroll
        for (int n = 0; n < 4; ++n) {
          const int r = wsc * 64 + n * 16 + lc;
#pragma unroll
          for (int kk = 0; kk < 2; ++kk)
            bg[n][kk] = *(const bf16x8*)(Bt + r * 128 + ((kk * 64 + lr * 16) ^ sw));
        }
        __builtin_amdgcn_s_setprio(1);
#pragma unroll
        for (int kk = 0; kk < 2; ++kk)
#pragma unroll
          for (int m = 0; m < 4; ++m)
#pragma unroll
            for (int n = 0; n < 4; ++n)
              acc[m][n] = __builtin_amdgcn_mfma_f32_16x16x32_bf16(af[m][kk], bg[n][kk], acc[m][n], 0, 0, 0);
        __builtin_amdgcn_s_setprio(0);
      }
      if (t + 2 < KT) asm volatile("s_waitcnt vmcnt(6)" ::: "memory");
      else            asm volatile("s_waitcnt vmcnt(0)" ::: "memory");
      __builtin_amdgcn_s_barrier();
      __builtin_amdgcn_sched_barrier(0);
    }

    // ---- fused epilogue: strict-lower mask, row-sums + col-sums + unif ----
    const bool unif = (I <= 7) || (I >= 8 && I <= 15 && J >= 16);
    const int  uidx = (I <= 7) ? 2 : 3;
    float u = 0.0f;
    if (useful) {
      float cs[4] = {0.0f, 0.0f, 0.0f, 0.0f};
#pragma unroll
      for (int m = 0; m < 4; ++m) {
        const int growb = rowA0 + wsr * 64 + m * 16 + lr * 4;
#pragma unroll
        for (int i = 0; i < 4; ++i) {
          const int grow = growb + i;
          float rs = 0.0f;
#pragma unroll
          for (int n = 0; n < 4; ++n) {
            const int gcol = colB0 + wsc * 64 + n * 16 + lc;
            const bool incl = (gcol < grow);
            float e = incl ? exp2f(acc[m][n][i] * RK10) : 0.0f;
            rs += e;
            cs[n] += e;
            if (unif) u += incl ? exp2f(acc[m][n][i] * K4 - K4) : 0.0f;
          }
          rs += __shfl_xor(rs, 1); rs += __shfl_xor(rs, 2);
          rs += __shfl_xor(rs, 4); rs += __shfl_xor(rs, 8);
          if (lc == 0 && rs > 0.0f) atomicAdd(&denom[grow], rs);
        }
      }
#pragma unroll
      for (int n = 0; n < 4; ++n) {
        float c = cs[n];
        c += __shfl_xor(c, 16); c += __shfl_xor(c, 32);
        if (lr == 0 && c > 0.0f) atomicAdd(&denom[colB0 + wsc * 64 + n * 16 + lc], c);
      }
    }
    if (unif) {
      for (int off = 1; off < 64; off <<= 1) u += __shfl_xor(u, off);
      if (lane == 0) red[wid] = u;
      __syncthreads();
      if (tid == 0) {
        float s8 = 0.0f;
#pragma unroll
        for (int i = 0; i < 8; ++i) s8 += red[i];
        atomicAdd(&scal[uidx], 2.0f * s8);   // each pair once; mirror via x2
      }
    }
  }
}

// ---------- kernel 3: reduce log(denom) + pos/align partials + final combine ----------
__global__ __launch_bounds__(1024) void klogf(const float* __restrict__ denom,
                                              const float* __restrict__ pp,
                                              const float* __restrict__ ap,
                                              const float* __restrict__ scal,
                                              float* __restrict__ out) {
  __shared__ float redl[16], redp[16], reda[16];
  const int tid = threadIdx.x;
  float s = 0.0f, sp = 0.0f, sa = 0.0f;
#pragma unroll
  for (int q = 0; q < 8; ++q) s += logf(denom[q * 1024 + tid]);
#pragma unroll
  for (int q = 0; q < 4; ++q) { sp += pp[q * 1024 + tid]; sa += ap[q * 1024 + tid]; }
  const int lane = tid & 63, w = tid >> 6;
  for (int off = 1; off < 64; off <<= 1) {
    s += __shfl_xor(s, off); sp += __shfl_xor(sp, off); sa += __shfl_xor(sa, off);
  }
  if (lane == 0) { redl[w] = s; redp[w] = sp; reda[w] = sa; }
  __syncthreads();
  if (tid == 0) {
    float S = 0.0f, SP = 0.0f, SA = 0.0f;
#pragma unroll
    for (int i = 0; i < 16; ++i) { S += redl[i]; SP += redp[i]; SA += reda[i]; }
    const float P = 2048.0f * 2047.0f * 0.5f;
    out[0] = (S - 20.0f * SP) / 8192.0f;    // (sum log d - 2*sum_pos/t) / 2n
    out[1] = SA / 4096.0f;                  // lalign
    out[2] = 0.5f * (logf(scal[2] * 0.5f / P) + logf(scal[3] * 0.5f / P));
  }
}

extern "C" void kernel_launch(void* const* d_in, const int* in_sizes, int n_in,
                              void* d_out, int out_size, void* d_ws, size_t ws_size,
                              hipStream_t stream) {
  const float* p1 = (const float*)d_in[0];
  const float* p2 = (const float*)d_in[1];
  float* out = (float*)d_out;
  char* ws = (char*)d_ws;
  unsigned short* z = (unsigned short*)ws;                    // 8192 x 1024 bf16 = 16 MB
  float* denom = (float*)(ws + (size_t)M_TOT * DDIM * 2);     // 8192 f32
  float* scal  = denom + M_TOT;                               // 8 f32 [., ., U0, U1]
  int*   ctr   = (int*)(scal + 8);                            // 8 ints (work counter)
  float* pp    = (float*)(ctr + 8);                           // 4096 pos partials
  float* ap    = pp + 4096;                                   // 4096 align partials

  (void)hipFuncSetAttribute((const void*)kgemm,
                            hipFuncAttributeMaxDynamicSharedMemorySize, LDS_TOTAL);
  hipMemsetAsync(denom, 0, (M_TOT + 8) * sizeof(float) + 8 * sizeof(int), stream);
  knorm<<<N_ROWS, 256, 0, stream>>>(p1, p2, z, pp, ap);
  kgemm<<<256, 512, LDS_TOTAL, stream>>>(z, denom, scal, ctr);
  klogf<<<1, 1024, 0, stream>>>(denom, pp, ap, scal, out);
}